// Round 10
// baseline (42.548 us; speedup 1.0000x reference)
//
#include <hip/hip_runtime.h>

// Problem constants (from reference: x [16, 32, 64, 32, 32] f32)
constexpr int T_DIM   = 16;
constexpr int B_DIM   = 32;
constexpr int FEAT    = 64 * 32 * 32;   // 65536 features per (t,b)
constexpr int THREADS = 256;
constexpr int NCHUNK  = 8;              // blocks per b -> 256 blocks = 1/CU
constexpr int FPB     = FEAT / NCHUNK;  // 8192 features per block
// Per iter: 4 waves x 256 floats (half-wave lane: va+vb float4 pair) = 1024
constexpr int ITERS   = FPB / 1024;     // 8

// Pass 1: t-split (lanes 0-31 own t=0..7, lanes 32-63 own t=8..15 of the SAME
// features), relu+cumsum in place, 1KB-per-plane-per-iter loads (va/vb).
// Stream-shape ladder (measured): 512B windows -> 34.6us; 1KB windows -> 34.6;
// 4KB sequential/wave + 512 blocks -> 30.2 (r9, -4.4us). This round extends
// the same lever: 256 blocks, 8KB sequential run per plane per wave,
// halving concurrent streams (128->64 per CU) and doubling run length.
// #pragma unroll 2 keeps exactly 2 iterations (32 x 1KB loads) in flight:
// enough MLP at 1 wave/SIMD without register blowup (~160 VGPR, no spill).
__global__ __launch_bounds__(THREADS) void snn_pass1(
    const float* __restrict__ x, float* __restrict__ partial) {
    const int b     = blockIdx.x;   // 0..31
    const int chunk = blockIdx.y;   // 0..NCHUNK-1
    const int tid   = threadIdx.x;
    const int lane  = tid & 63;
    const int wave  = tid >> 6;
    const int half  = lane >> 5;    // 0: t=0..7, 1: t=8..15
    const int sub   = lane & 31;

    const size_t tstride  = (size_t)B_DIM * FEAT;  // floats between t-planes
    const size_t tstride4 = tstride / 4;           // in float4 units
    const float* xb = x + (size_t)b * FEAT + (size_t)half * 8 * tstride;

    float accA[8], accB[8];
#pragma unroll
    for (int k = 0; k < 8; ++k) { accA[k] = 0.f; accB[k] = 0.f; }

#pragma unroll 2
    for (int it = 0; it < ITERS; ++it) {
        // wave-contiguous: wave w covers [w*8KB, (w+1)*8KB) of the block's
        // window, advancing 256 floats (1KB) per iteration.
        const int base = chunk * FPB + wave * 2048 + it * 256;
        const float4* p = reinterpret_cast<const float4*>(xb + base) + sub;

        float4 va[8], vb[8];
#pragma unroll
        for (int k = 0; k < 8; ++k) {
            va[k] = p[(size_t)k * tstride4];        // floats [0,128) of window
            vb[k] = p[(size_t)k * tstride4 + 32];   // floats [128,256)
        }

        // relu + in-place cumsum (va/vb become s[half*8+k])
        float4 ra = make_float4(0.f, 0.f, 0.f, 0.f);
        float4 rb = make_float4(0.f, 0.f, 0.f, 0.f);
#pragma unroll
        for (int k = 0; k < 8; ++k) {
            ra.x += fmaxf(va[k].x, 0.f); ra.y += fmaxf(va[k].y, 0.f);
            ra.z += fmaxf(va[k].z, 0.f); ra.w += fmaxf(va[k].w, 0.f);
            va[k] = ra;
            rb.x += fmaxf(vb[k].x, 0.f); rb.y += fmaxf(vb[k].y, 0.f);
            rb.z += fmaxf(vb[k].z, 0.f); rb.w += fmaxf(vb[k].w, 0.f);
            vb[k] = rb;
        }

        // cross-half stitch: 8 shuffles
        float4 oa, ob;
        oa.x = __shfl_xor(ra.x, 32, 64); oa.y = __shfl_xor(ra.y, 32, 64);
        oa.z = __shfl_xor(ra.z, 32, 64); oa.w = __shfl_xor(ra.w, 32, 64);
        ob.x = __shfl_xor(rb.x, 32, 64); ob.y = __shfl_xor(rb.y, 32, 64);
        ob.z = __shfl_xor(rb.z, 32, 64); ob.w = __shfl_xor(rb.w, 32, 64);

        const float4 s15a = make_float4(ra.x + oa.x, ra.y + oa.y,
                                        ra.z + oa.z, ra.w + oa.w);
        const float4 s15b = make_float4(rb.x + ob.x, rb.y + ob.y,
                                        rb.z + ob.z, rb.w + ob.w);
        const float hb = (float)half;  // upper half adds lower's s[7] as base
        const float4 ba = make_float4(oa.x * hb, oa.y * hb, oa.z * hb, oa.w * hb);
        const float4 bb = make_float4(ob.x * hb, ob.y * hb, ob.z * hb, ob.w * hb);

#pragma unroll
        for (int k = 0; k < 8; ++k) {
            const float invt = half ? (1.f / (float)(k + 9))
                                    : (1.f / (float)(k + 1));
            const float ax = va[k].x + ba.x, ay = va[k].y + ba.y,
                        az = va[k].z + ba.z, aw = va[k].w + ba.w;
            const float bx = vb[k].x + bb.x, by = vb[k].y + bb.y,
                        bz = vb[k].z + bb.z, bw = vb[k].w + bb.w;
            accA[k] += (ax * ax + ay * ay + az * az + aw * aw +
                        bx * bx + by * by + bz * bz + bw * bw) * (invt * invt);
            accB[k] += (ax * s15a.x + ay * s15a.y + az * s15a.z + aw * s15a.w +
                        bx * s15b.x + by * s15b.y + bz * s15b.z + bw * s15b.w)
                       * (invt * 0.0625f);
        }
    }

    // Reduce within each 32-lane half (xor masks <32 stay inside the half).
#pragma unroll
    for (int k = 0; k < 8; ++k) {
#pragma unroll
        for (int m = 16; m; m >>= 1) {
            accA[k] += __shfl_xor(accA[k], m, 64);
            accB[k] += __shfl_xor(accB[k], m, 64);
        }
    }

    __shared__ float red[4][32];
    if (sub == 0) {  // lane 0 (t=0..7) and lane 32 (t=8..15) per wave
#pragma unroll
        for (int k = 0; k < 8; ++k) {
            red[wave][half * 8 + k]      = accA[k];
            red[wave][16 + half * 8 + k] = accB[k];
        }
    }
    __syncthreads();
    if (tid < 32) {
        const float s4 = red[0][tid] + red[1][tid] + red[2][tid] + red[3][tid];
        partial[((size_t)b * NCHUNK + chunk) * 32 + tid] = s4;
    }
}

// Pass 2: reduce chunks, finalize per-b scalar.
__global__ __launch_bounds__(64) void snn_finalize(
    const float* __restrict__ partial, float* __restrict__ out) {
    const int b   = blockIdx.x;   // 0..31
    const int tid = threadIdx.x;  // 64 threads = 1 wave
    const int v   = tid & 31;     // value index 0..31
    const int h   = tid >> 5;     // chunk half

    float acc = 0.f;
#pragma unroll
    for (int i = 0; i < NCHUNK / 2; ++i) {
        const int c = h * (NCHUNK / 2) + i;
        acc += partial[((size_t)b * NCHUNK + c) * 32 + v];
    }
    acc += __shfl_xor(acc, 32, 64);  // lanes 0..31 now hold full sums

    __shared__ float sA[16];
    __shared__ float sB[16];
    if (tid < 16)      sA[tid] = acc;
    else if (tid < 32) sB[tid - 16] = acc;
    __syncthreads();

    if (tid == 0) {
        const float n15 = sqrtf(sA[15] + 1e-5f);
        float csum = 0.f;
#pragma unroll
        for (int t = 0; t < 16; ++t) {
            const float nt = sqrtf(sA[t] + 1e-5f);
            csum += sB[t] / (nt * n15);
        }
        const float cs = csum * (1.f / 16.f);
        out[b] = 1.f / (cs + 1e-5f);
    }
}

extern "C" void kernel_launch(void* const* d_in, const int* in_sizes, int n_in,
                              void* d_out, int out_size, void* d_ws, size_t ws_size,
                              hipStream_t stream) {
    const float* x   = (const float*)d_in[0];  // [16, 32, 64, 32, 32]
    float* out       = (float*)d_out;          // [1, 32]
    float* partial   = (float*)d_ws;           // 32 * 8 * 32 floats = 32 KB

    dim3 grid1(B_DIM, NCHUNK);
    snn_pass1<<<grid1, THREADS, 0, stream>>>(x, partial);
    snn_finalize<<<B_DIM, 64, 0, stream>>>(partial, out);
}

// Round 11
// 32.397 us; speedup vs baseline: 1.3133x; 1.3133x over previous
//
#include <hip/hip_runtime.h>

// Problem constants (from reference: x [16, 32, 64, 32, 32] f32)
constexpr int T_DIM   = 16;
constexpr int B_DIM   = 32;
constexpr int FEAT    = 64 * 32 * 32;   // 65536 features per (t,b)
constexpr int THREADS = 256;            // 4 waves
constexpr int NCHUNK  = 32;             // blocks per b -> 1024 blocks
constexpr int FPB     = FEAT / NCHUNK;  // 2048 features per block (8KB/plane)

__device__ __forceinline__ float4 relu4(float4 a) {
    return make_float4(fmaxf(a.x, 0.f), fmaxf(a.y, 0.f),
                       fmaxf(a.z, 0.f), fmaxf(a.w, 0.f));
}
__device__ __forceinline__ float4 add4(float4 a, float4 b) {
    return make_float4(a.x + b.x, a.y + b.y, a.z + b.z, a.w + b.w);
}
__device__ __forceinline__ float dot4(float4 a, float4 b) {
    return a.x * b.x + a.y * b.y + a.z * b.z + a.w * b.w;
}

// Pass 1, wave-per-plane-group: wave w owns t-planes 4w..4w+3 and reads each
// as ONE dense sequential 8KB stream (8 x 1KB coalesced loads). Streams/CU
// drop ~128 (r9) -> ~48 and double in length -- extending the measured
// stream-shape lever (r9: -4.4us) while keeping >=12 waves/CU (r10's TLP
// collapse at 1 wave/SIMD is avoided). Cross-wave cumsum prefix via one LDS
// exchange of per-wave totals. All 32 data float4 preloaded (full MLP burst),
// cumsum in place, exchange consumed per-i to cap transient registers.
// No launch_bounds cap (r2/r3: cap => 50MB spill), no outer unroll pragmas.
__global__ __launch_bounds__(THREADS) void snn_pass1(
    const float* __restrict__ x, float* __restrict__ partial) {
    const int b     = blockIdx.x;   // 0..31
    const int chunk = blockIdx.y;   // 0..NCHUNK-1
    const int tid   = threadIdx.x;
    const int lane  = tid & 63;
    const int wave  = tid >> 6;     // owns planes 4w..4w+3

    const size_t tstride  = (size_t)B_DIM * FEAT;  // floats between t-planes
    const size_t foff     = (size_t)b * FEAT + (size_t)chunk * FPB;

    // Preload: v[k][i] = plane (4*wave+k), 1KB chunk i, this lane's float4.
    float4 v[4][8];
#pragma unroll
    for (int k = 0; k < 4; ++k) {
        const float4* p = reinterpret_cast<const float4*>(x)
                        + (((size_t)(4 * wave + k) * tstride + foff) >> 2) + lane;
#pragma unroll
        for (int i = 0; i < 8; ++i) v[k][i] = p[i * 64];
    }

    // relu + in-place cumsum across this wave's 4 planes.
#pragma unroll
    for (int i = 0; i < 8; ++i) v[0][i] = relu4(v[0][i]);
#pragma unroll
    for (int k = 1; k < 4; ++k)
#pragma unroll
        for (int i = 0; i < 8; ++i) v[k][i] = add4(relu4(v[k][i]), v[k - 1][i]);

    // Exchange per-wave totals L_w = v[3][i].  Layout [i*4+w][lane]: lanes
    // dense 16B apart -> minimal-conflict b128 LDS ops.
    __shared__ float4 xch[32][64];   // 32 KB
#pragma unroll
    for (int i = 0; i < 8; ++i) xch[i * 4 + wave][lane] = v[3][i];
    __syncthreads();

    float invt[4];
#pragma unroll
    for (int k = 0; k < 4; ++k) invt[k] = 1.f / (float)(4 * wave + k + 1);

    float accA[4], accB[4];
#pragma unroll
    for (int k = 0; k < 4; ++k) { accA[k] = 0.f; accB[k] = 0.f; }

#pragma unroll
    for (int i = 0; i < 8; ++i) {
        float4 base = make_float4(0.f, 0.f, 0.f, 0.f);
        float4 tot  = v[3][i];   // own total
#pragma unroll
        for (int u = 0; u < 4; ++u) {
            if (u != wave) {                    // wave-uniform branch
                const float4 Lu = xch[i * 4 + u][lane];
                tot = add4(tot, Lu);
                if (u < wave) base = add4(base, Lu);
            }
        }
#pragma unroll
        for (int k = 0; k < 4; ++k) {
            const float4 s = add4(v[k][i], base);
            accA[k] += dot4(s, s) * invt[k] * invt[k];
            accB[k] += dot4(s, tot) * invt[k] * 0.0625f;
        }
    }

    // Full 64-lane reduction of the 8 per-lane scalars.
#pragma unroll
    for (int k = 0; k < 4; ++k) {
#pragma unroll
        for (int m = 32; m; m >>= 1) {
            accA[k] += __shfl_xor(accA[k], m, 64);
            accB[k] += __shfl_xor(accB[k], m, 64);
        }
    }

    __shared__ float red[32];
    __syncthreads();                 // xch reads done before red reuse window
    if (lane == 0) {
#pragma unroll
        for (int k = 0; k < 4; ++k) {
            red[4 * wave + k]      = accA[k];
            red[16 + 4 * wave + k] = accB[k];
        }
    }
    __syncthreads();
    if (tid < 32)
        partial[((size_t)b * NCHUNK + chunk) * 32 + tid] = red[tid];
}

// Pass 2: reduce chunks, finalize per-b scalar.
__global__ __launch_bounds__(64) void snn_finalize(
    const float* __restrict__ partial, float* __restrict__ out) {
    const int b   = blockIdx.x;   // 0..31
    const int tid = threadIdx.x;  // 64 threads = 1 wave
    const int v   = tid & 31;     // value index 0..31
    const int h   = tid >> 5;     // chunk half

    float acc = 0.f;
#pragma unroll
    for (int i = 0; i < NCHUNK / 2; ++i) {
        const int c = h * (NCHUNK / 2) + i;
        acc += partial[((size_t)b * NCHUNK + c) * 32 + v];
    }
    acc += __shfl_xor(acc, 32, 64);  // lanes 0..31 now hold full sums

    __shared__ float sA[16];
    __shared__ float sB[16];
    if (tid < 16)      sA[tid] = acc;
    else if (tid < 32) sB[tid - 16] = acc;
    __syncthreads();

    if (tid == 0) {
        const float n15 = sqrtf(sA[15] + 1e-5f);
        float csum = 0.f;
#pragma unroll
        for (int t = 0; t < 16; ++t) {
            const float nt = sqrtf(sA[t] + 1e-5f);
            csum += sB[t] / (nt * n15);
        }
        const float cs = csum * (1.f / 16.f);
        out[b] = 1.f / (cs + 1e-5f);
    }
}

extern "C" void kernel_launch(void* const* d_in, const int* in_sizes, int n_in,
                              void* d_out, int out_size, void* d_ws, size_t ws_size,
                              hipStream_t stream) {
    const float* x   = (const float*)d_in[0];  // [16, 32, 64, 32, 32]
    float* out       = (float*)d_out;          // [1, 32]
    float* partial   = (float*)d_ws;           // 32 * 32 * 32 floats = 128 KB

    dim3 grid1(B_DIM, NCHUNK);
    snn_pass1<<<grid1, THREADS, 0, stream>>>(x, partial);
    snn_finalize<<<B_DIM, 64, 0, stream>>>(partial, out);
}

// Round 13
// 30.657 us; speedup vs baseline: 1.3879x; 1.0568x over previous
//
#include <hip/hip_runtime.h>

// Problem constants (from reference: x [16, 32, 64, 32, 32] f32)
constexpr int T_DIM   = 16;
constexpr int B_DIM   = 32;
constexpr int FEAT    = 64 * 32 * 32;   // 65536 features per (t,b)
constexpr int THREADS = 256;
constexpr int NCHUNK  = 16;             // blocks per b -> 512 blocks total
constexpr int FPB     = FEAT / NCHUNK;  // 4096 features per block
// Per iter: 4 waves x 256 floats (half-wave lane: va+vb float4 pair) = 1024
constexpr int ITERS   = FPB / 1024;     // 4

// Native vector type for __builtin_nontemporal_load (HIP_vector_type is a
// struct and is rejected by the builtin; ext_vector_type works).
typedef float f4 __attribute__((ext_vector_type(4)));

// Pass 1 == round 9's winner (30.2 us; r10/r11 stream-shape extensions both
// regressed, so this shape is locked) + ONE delta: nontemporal loads.
// x is read exactly once -> L2/L3 read-allocate is pure overhead for these
// 128 single-use streams/CU; `nt` bypasses allocation on the fetch path.
// If neutral/worse, revert to r9 exactly and declare pattern roofline.
__global__ __launch_bounds__(THREADS) void snn_pass1(
    const float* __restrict__ x, float* __restrict__ partial) {
    const int b     = blockIdx.x;   // 0..31
    const int chunk = blockIdx.y;   // 0..NCHUNK-1
    const int tid   = threadIdx.x;
    const int lane  = tid & 63;
    const int wave  = tid >> 6;
    const int half  = lane >> 5;    // 0: t=0..7, 1: t=8..15
    const int sub   = lane & 31;

    const size_t tstride  = (size_t)B_DIM * FEAT;  // floats between t-planes
    const size_t tstride4 = tstride / 4;           // in float4 units
    const float* xb = x + (size_t)b * FEAT + (size_t)half * 8 * tstride;

    float accA[8], accB[8];
#pragma unroll
    for (int k = 0; k < 8; ++k) { accA[k] = 0.f; accB[k] = 0.f; }

#pragma unroll
    for (int it = 0; it < ITERS; ++it) {
        // wave-contiguous: wave w covers [w*4KB, (w+1)*4KB) of the block's
        // window, advancing 256 floats (1KB) per iteration.
        const int base = chunk * FPB + wave * 1024 + it * 256;
        const f4* p = reinterpret_cast<const f4*>(xb + base) + sub;

        f4 va[8], vb[8];
#pragma unroll
        for (int k = 0; k < 8; ++k) {
            va[k] = __builtin_nontemporal_load(p + (size_t)k * tstride4);
            vb[k] = __builtin_nontemporal_load(p + (size_t)k * tstride4 + 32);
        }

        // relu + in-place cumsum (va/vb become s[half*8+k])
        f4 ra = {0.f, 0.f, 0.f, 0.f};
        f4 rb = {0.f, 0.f, 0.f, 0.f};
#pragma unroll
        for (int k = 0; k < 8; ++k) {
            ra.x += fmaxf(va[k].x, 0.f); ra.y += fmaxf(va[k].y, 0.f);
            ra.z += fmaxf(va[k].z, 0.f); ra.w += fmaxf(va[k].w, 0.f);
            va[k] = ra;
            rb.x += fmaxf(vb[k].x, 0.f); rb.y += fmaxf(vb[k].y, 0.f);
            rb.z += fmaxf(vb[k].z, 0.f); rb.w += fmaxf(vb[k].w, 0.f);
            vb[k] = rb;
        }

        // cross-half stitch: 8 shuffles
        f4 oa, ob;
        oa.x = __shfl_xor(ra.x, 32, 64); oa.y = __shfl_xor(ra.y, 32, 64);
        oa.z = __shfl_xor(ra.z, 32, 64); oa.w = __shfl_xor(ra.w, 32, 64);
        ob.x = __shfl_xor(rb.x, 32, 64); ob.y = __shfl_xor(rb.y, 32, 64);
        ob.z = __shfl_xor(rb.z, 32, 64); ob.w = __shfl_xor(rb.w, 32, 64);

        const f4 s15a = ra + oa;
        const f4 s15b = rb + ob;
        const float hb = (float)half;  // upper half adds lower's s[7] as base
        const f4 ba = oa * hb;
        const f4 bb = ob * hb;

#pragma unroll
        for (int k = 0; k < 8; ++k) {
            const float invt = half ? (1.f / (float)(k + 9))
                                    : (1.f / (float)(k + 1));
            const f4 sa = va[k] + ba;
            const f4 sb = vb[k] + bb;
            accA[k] += (sa.x * sa.x + sa.y * sa.y + sa.z * sa.z + sa.w * sa.w +
                        sb.x * sb.x + sb.y * sb.y + sb.z * sb.z + sb.w * sb.w)
                       * (invt * invt);
            accB[k] += (sa.x * s15a.x + sa.y * s15a.y + sa.z * s15a.z +
                        sa.w * s15a.w + sb.x * s15b.x + sb.y * s15b.y +
                        sb.z * s15b.z + sb.w * s15b.w) * (invt * 0.0625f);
        }
    }

    // Reduce within each 32-lane half (xor masks <32 stay inside the half).
#pragma unroll
    for (int k = 0; k < 8; ++k) {
#pragma unroll
        for (int m = 16; m; m >>= 1) {
            accA[k] += __shfl_xor(accA[k], m, 64);
            accB[k] += __shfl_xor(accB[k], m, 64);
        }
    }

    __shared__ float red[4][32];
    if (sub == 0) {  // lane 0 (t=0..7) and lane 32 (t=8..15) per wave
#pragma unroll
        for (int k = 0; k < 8; ++k) {
            red[wave][half * 8 + k]      = accA[k];
            red[wave][16 + half * 8 + k] = accB[k];
        }
    }
    __syncthreads();
    if (tid < 32) {
        const float s4 = red[0][tid] + red[1][tid] + red[2][tid] + red[3][tid];
        partial[((size_t)b * NCHUNK + chunk) * 32 + tid] = s4;
    }
}

// Pass 2: reduce chunks, finalize per-b scalar.
__global__ __launch_bounds__(64) void snn_finalize(
    const float* __restrict__ partial, float* __restrict__ out) {
    const int b   = blockIdx.x;   // 0..31
    const int tid = threadIdx.x;  // 64 threads = 1 wave
    const int v   = tid & 31;     // value index 0..31
    const int h   = tid >> 5;     // chunk half

    float acc = 0.f;
#pragma unroll
    for (int i = 0; i < NCHUNK / 2; ++i) {
        const int c = h * (NCHUNK / 2) + i;
        acc += partial[((size_t)b * NCHUNK + c) * 32 + v];
    }
    acc += __shfl_xor(acc, 32, 64);  // lanes 0..31 now hold full sums

    __shared__ float sA[16];
    __shared__ float sB[16];
    if (tid < 16)      sA[tid] = acc;
    else if (tid < 32) sB[tid - 16] = acc;
    __syncthreads();

    if (tid == 0) {
        const float n15 = sqrtf(sA[15] + 1e-5f);
        float csum = 0.f;
#pragma unroll
        for (int t = 0; t < 16; ++t) {
            const float nt = sqrtf(sA[t] + 1e-5f);
            csum += sB[t] / (nt * n15);
        }
        const float cs = csum * (1.f / 16.f);
        out[b] = 1.f / (cs + 1e-5f);
    }
}

extern "C" void kernel_launch(void* const* d_in, const int* in_sizes, int n_in,
                              void* d_out, int out_size, void* d_ws, size_t ws_size,
                              hipStream_t stream) {
    const float* x   = (const float*)d_in[0];  // [16, 32, 64, 32, 32]
    float* out       = (float*)d_out;          // [1, 32]
    float* partial   = (float*)d_ws;           // 32 * 16 * 32 floats = 64 KB

    dim3 grid1(B_DIM, NCHUNK);
    snn_pass1<<<grid1, THREADS, 0, stream>>>(x, partial);
    snn_finalize<<<B_DIM, 64, 0, stream>>>(partial, out);
}